// Round 3
// baseline (6952.459 us; speedup 1.0000x reference)
//
#include <hip/hip_runtime.h>

// ---------------------------------------------------------------------------
// WindowAttention2D on MI355X — low-workspace variant.
//   gemm_qkv: qkv[M][1536]f32 = x[M][512]f32 @ w_qkv, via 3-term f16 split
//             (A reg-staged+converted on the fly; B pre-split in ws)
//   attn:     per (window w, col r): rmsnorm(q,k), scores+bias+mask, softmax,
//             PV; writes O as [hi|lo|hi*2^-11] f16 IN-PLACE into its own qkv
//             rows (u16 offsets 1024..2560 of the 3072-u16 row)
//   gemm_proj: d_out = Os @ w_projT + b_proj  (A via global_load_lds, lda=3072)
// Split accuracy: x*w ~ xh*wh + xl*wh + (xh*2^-11)*(wl*2^11); all f16 factors
// normal-range (no subnormal-flush risk); error ~1e-5.
// ws: qkv 981,467,136 | BqT 4,718,592 | BpT 1,572,864  => 987,758,592 B.
// If ws_size is smaller: write 1e30 sentinel to d_out (diagnosable absmax).
// ---------------------------------------------------------------------------

typedef unsigned short u16;
typedef unsigned int   u32;
typedef _Float16 f16x8 __attribute__((ext_vector_type(8)));
typedef float    f32x4 __attribute__((ext_vector_type(4)));

#define MTOK   159744      // 128 * 1248 token rows (x-natural order)
#define NROWS  1248

__device__ __forceinline__ u16 f2h_bits(float f) {
    union { _Float16 h; u16 u; } cv; cv.h = (_Float16)f; return cv.u;
}
__device__ __forceinline__ float h2f_bits(u16 u) {
    union { _Float16 h; u16 u; } cv; cv.u = u; return (float)cv.h;
}

__device__ __forceinline__ void gld_lds16(const void* g, void* l) {
    __builtin_amdgcn_global_load_lds((__attribute__((address_space(1))) void*)g,
                                     (__attribute__((address_space(3))) void*)l,
                                     16, 0, 0);
}

// --------------------------- sentinel (ws too small) ------------------------
__global__ void sentinel_kernel(float* __restrict__ out, int n) {
    for (int i = blockIdx.x * blockDim.x + threadIdx.x; i < n;
         i += gridDim.x * blockDim.x)
        out[i] = 1.0e30f;
}

// --------------------------- weight split ----------------------------------
// BT[n][k'], k' in [0,1536): part0 (k'<512) = hi(w[ks][n]); part1 = hi;
// part2 = (w - hi)*2048  (exact-product pairing with A's hi*2^-11).
__global__ void split_w_kernel(const float* __restrict__ Wsrc, u16* __restrict__ BT, int N) {
    const size_t total = (size_t)N * 1536;
    for (size_t idx = (size_t)blockIdx.x * blockDim.x + threadIdx.x; idx < total;
         idx += (size_t)gridDim.x * blockDim.x) {
        const int kp = (int)(idx % 1536);
        const size_t nrow = idx / 1536;
        const int part = kp >> 9, ks = kp & 511;
        const float f = Wsrc[(size_t)ks * N + nrow];
        const u16 h = f2h_bits(f);
        BT[idx] = (part < 2) ? h : f2h_bits((f - h2f_bits(h)) * 2048.0f);
    }
}

// --------------------------- QKV GEMM --------------------------------------
// C[M][1536] = split3(x) @ BqT^T.  128x128 tile, BK=64, 24 K-steps.
// A staged from f32 x in-regs (convert per part), XOR-swizzled LDS writes.
// B staged via global_load_lds (linear LDS).
__global__ __launch_bounds__(256, 3) void gemm_qkv(
    const float* __restrict__ x, const u16* __restrict__ BT, float* __restrict__ C)
{
    __shared__ u16 As[128 * 64];
    __shared__ u16 Bs[128 * 64];

    const int NT = 12;
    const int per = gridDim.x >> 3;
    const int lin = (blockIdx.x & 7) * per + (blockIdx.x >> 3);
    const int nt = lin % NT, mt = lin / NT;
    const int m0 = mt * 128, n0 = nt * 128;

    const int tid  = threadIdx.x;
    const int lane = tid & 63;
    const int wid  = tid >> 6;
    const int wr = wid >> 1, wc = wid & 1;

    const int srow = lane >> 3;          // B staging: row within 8-row chunk
    const int scol = (lane & 7) * 8;     // B staging: k offset (u16)
    const int ar = tid >> 2;             // A staging: row (pass*64 + ar)
    const int aq = tid & 3;              // A staging: 16-float quad id

    f32x4 acc[4][4] = {};

    for (int kt = 0; kt < 24; ++kt) {
        const int part = kt >> 3;            // 0:hi 1:lo 2:hi*2^-11
        const int ksb  = (kt & 7) * 64;      // source k in x
        const int bkk  = kt * 64;            // k' in BT

        // B: async global->LDS (issue first, overlaps A conversion)
#pragma unroll
        for (int q = 0; q < 4; ++q) {
            const int c = wid * 4 + q;
            gld_lds16(BT + (size_t)(n0 + c * 8 + srow) * 1536 + bkk + scol, &Bs[c * 512]);
        }

        // A: load f32, convert, swizzled ds_write
#pragma unroll
        for (int P = 0; P < 2; ++P) {
            const int r = P * 64 + ar;
            const float* src = x + (size_t)(m0 + r) * 512 + ksb + aq * 16;
            float4 f0 = ((const float4*)src)[0];
            float4 f1 = ((const float4*)src)[1];
            float4 f2 = ((const float4*)src)[2];
            float4 f3 = ((const float4*)src)[3];
            float fv[16] = {f0.x,f0.y,f0.z,f0.w, f1.x,f1.y,f1.z,f1.w,
                            f2.x,f2.y,f2.z,f2.w, f3.x,f3.y,f3.z,f3.w};
            union { u16 u[16]; uint4 q4[2]; } pkv;
#pragma unroll
            for (int j = 0; j < 16; ++j) {
                const u16 h = f2h_bits(fv[j]);
                pkv.u[j] = (part == 0) ? h
                         : (part == 1) ? f2h_bits(fv[j] - h2f_bits(h))
                                       : f2h_bits(h2f_bits(h) * (1.0f / 2048.0f));
            }
            const u32 byt = (u32)(r * 128 + aq * 32);
            const u32 sw  = (u32)((r & 7) << 4);
            *(uint4*)((char*)As + ((byt)      ^ sw)) = pkv.q4[0];
            *(uint4*)((char*)As + ((byt + 16) ^ sw)) = pkv.q4[1];
        }
        __syncthreads();

#pragma unroll
        for (int ks = 0; ks < 2; ++ks) {
            const int ko = ks * 32 + (lane >> 4) * 8;
            const int rl = lane & 15;
            const u32 sw = (u32)((rl & 7) << 4);
            f16x8 af[4], bfr[4];
#pragma unroll
            for (int i = 0; i < 4; ++i) {
                const int arow = wr * 64 + i * 16 + rl;
                af[i]  = *(const f16x8*)((const char*)As + (((u32)(arow * 128 + ko * 2)) ^ sw));
                bfr[i] = *(const f16x8*)&Bs[(wc * 64 + i * 16 + rl) * 64 + ko];
            }
#pragma unroll
            for (int i = 0; i < 4; ++i)
#pragma unroll
                for (int j = 0; j < 4; ++j)
                    acc[i][j] = __builtin_amdgcn_mfma_f32_16x16x32_f16(af[i], bfr[j], acc[i][j], 0, 0, 0);
        }
        __syncthreads();
    }

    // C/D: col = lane&15, row = (lane>>4)*4 + reg
    const int lr = (lane >> 4) * 4, lc = lane & 15;
#pragma unroll
    for (int i = 0; i < 4; ++i) {
        const int row = m0 + wr * 64 + i * 16 + lr;
#pragma unroll
        for (int j = 0; j < 4; ++j) {
            const int col = n0 + wc * 64 + j * 16 + lc;
            float* cp = C + (size_t)row * 1536 + col;
#pragma unroll
            for (int v = 0; v < 4; ++v) cp[(size_t)v * 1536] = acc[i][j][v];
        }
    }
}

// --------------------------- attention ------------------------------------
// block = (window w, col r): 512 threads, wave h = head h.
// lane: n = lane&31 (token), dh = lane>>5 (32-dim half).
// All global reads complete before the __syncthreads that precedes any
// write, and rows are block-exclusive -> in-place O write into qkv is safe.
__global__ __launch_bounds__(512, 2) void attn_kernel(
    float* __restrict__ qkv, const float* __restrict__ relpos,
    const float* __restrict__ qn_w, const float* __restrict__ kn_w)
{
    __shared__ float kn[8][32][68];   // +4 pad: staging-write bank spread
    __shared__ float vv[8][32][68];
    __shared__ float bias_s[8][63];
    __shared__ float qw[64], kw[64];

    const int b = blockIdx.x;
    const int w = b / NROWS, r = b - w * NROWS;
    const int tid  = threadIdx.x;
    const int hd_  = tid >> 6;         // head
    const int lane = tid & 63;
    const int n  = lane & 31;
    const int dh = lane >> 5;

    if (tid < 64) qw[tid] = qn_w[tid];
    else if (tid < 128) kw[tid - 64] = kn_w[tid - 64];
    if (lane < 63) bias_s[hd_][lane] = relpos[(size_t)(lane * 311 + 155) * 8 + hd_];
    __syncthreads();

    const size_t row = (size_t)((w * 32 + n + 16) & 127) * NROWS + r;
    const float* qsrc = qkv + row * 1536 + hd_ * 64 + dh * 32;

    // q -> regs (rmsnorm'd)
    float qf[32]; float ss = 0.f;
#pragma unroll
    for (int t = 0; t < 8; ++t) {
        float4 v4 = ((const float4*)qsrc)[t];
        qf[t*4]=v4.x; qf[t*4+1]=v4.y; qf[t*4+2]=v4.z; qf[t*4+3]=v4.w;
        ss += v4.x*v4.x + v4.y*v4.y + v4.z*v4.z + v4.w*v4.w;
    }
    ss += __shfl_xor(ss, 32, 64);
    const float rsq_q = rsqrtf(ss * (1.f/64.f) + 1e-6f);
#pragma unroll
    for (int t = 0; t < 32; ++t) qf[t] = qf[t] * rsq_q * qw[dh*32 + t];

    // k -> LDS (rmsnorm'd)
    { float kf[32]; float sk = 0.f;
#pragma unroll
      for (int t = 0; t < 8; ++t) {
          float4 v4 = ((const float4*)(qsrc + 512))[t];
          kf[t*4]=v4.x; kf[t*4+1]=v4.y; kf[t*4+2]=v4.z; kf[t*4+3]=v4.w;
          sk += v4.x*v4.x + v4.y*v4.y + v4.z*v4.z + v4.w*v4.w;
      }
      sk += __shfl_xor(sk, 32, 64);
      const float rsq_k = rsqrtf(sk * (1.f/64.f) + 1e-6f);
#pragma unroll
      for (int t = 0; t < 32; ++t) kn[hd_][n][dh*32 + t] = kf[t] * rsq_k * kw[dh*32 + t];
    }
    // v -> LDS raw
#pragma unroll
    for (int t = 0; t < 8; ++t)
        ((float4*)&vv[hd_][n][dh*32])[t] = ((const float4*)(qsrc + 1024))[t];
    __syncthreads();   // ALL global reads of this block's rows are now done

    // scores (partial over 32-dim half, combine across halves)
    float S[32];
#pragma unroll
    for (int m = 0; m < 32; ++m) {
        const float4* kr = (const float4*)&kn[hd_][m][dh*32];
        float s = 0.f;
#pragma unroll
        for (int t = 0; t < 8; ++t) {
            float4 k4 = kr[t];
            s += qf[t*4]*k4.x + qf[t*4+1]*k4.y + qf[t*4+2]*k4.z + qf[t*4+3]*k4.w;
        }
        S[m] = s;
    }
#pragma unroll
    for (int m = 0; m < 32; ++m) S[m] += __shfl_xor(S[m], 32, 64);

    float mx = -3.0e38f;
#pragma unroll
    for (int m = 0; m < 32; ++m) {
        float sv = S[m] * 0.125f + bias_s[hd_][n - m + 31];
        if (w == 3 && ((n < 16) != (m < 16))) sv = -1.0e9f;
        S[m] = sv; mx = fmaxf(mx, sv);
    }
    float den = 0.f;
#pragma unroll
    for (int m = 0; m < 32; ++m) { float p = __expf(S[m] - mx); S[m] = p; den += p; }
    const float inv = 1.f / den;

    // PV
    float o[32];
#pragma unroll
    for (int t = 0; t < 32; ++t) o[t] = 0.f;
#pragma unroll
    for (int m = 0; m < 32; ++m) {
        const float p = S[m];
        const float4* vr = (const float4*)&vv[hd_][m][dh*32];
#pragma unroll
        for (int t = 0; t < 8; ++t) {
            float4 v4 = vr[t];
            o[t*4] += p*v4.x; o[t*4+1] += p*v4.y; o[t*4+2] += p*v4.z; o[t*4+3] += p*v4.w;
        }
    }

    // In-place O write: row u16 base +1024: [hi | lo | hi*2^-11], 512 u16 each
    u16 hb[32], lb[32], sb[32];
#pragma unroll
    for (int t = 0; t < 32; ++t) {
        const float f = o[t] * inv;
        const u16 hh = f2h_bits(f);
        hb[t] = hh;
        lb[t] = f2h_bits(f - h2f_bits(hh));
        sb[t] = f2h_bits(h2f_bits(hh) * (1.0f / 2048.0f));
    }
    u16* ob = (u16*)qkv + row * 3072 + 1024 + hd_ * 64 + dh * 32;
    union { u16 u[32]; uint4 q4[4]; } pb;
#pragma unroll
    for (int t = 0; t < 32; ++t) pb.u[t] = hb[t];
    ((uint4*)(ob))[0] = pb.q4[0]; ((uint4*)(ob))[1] = pb.q4[1];
    ((uint4*)(ob))[2] = pb.q4[2]; ((uint4*)(ob))[3] = pb.q4[3];
#pragma unroll
    for (int t = 0; t < 32; ++t) pb.u[t] = lb[t];
    ((uint4*)(ob + 512))[0] = pb.q4[0]; ((uint4*)(ob + 512))[1] = pb.q4[1];
    ((uint4*)(ob + 512))[2] = pb.q4[2]; ((uint4*)(ob + 512))[3] = pb.q4[3];
#pragma unroll
    for (int t = 0; t < 32; ++t) pb.u[t] = sb[t];
    ((uint4*)(ob + 1024))[0] = pb.q4[0]; ((uint4*)(ob + 1024))[1] = pb.q4[1];
    ((uint4*)(ob + 1024))[2] = pb.q4[2]; ((uint4*)(ob + 1024))[3] = pb.q4[3];
}

// --------------------------- proj GEMM -------------------------------------
// d_out[M][512] = Os @ BpT^T + b_proj.  Os rows live inside qkv rows:
// u16 base = row*3072 + 1024, K' = 24*64 linear (akk = 1024 + kt*64).
__global__ __launch_bounds__(256, 3) void gemm_proj(
    const u16* __restrict__ Os, const u16* __restrict__ BT,
    float* __restrict__ C, const float* __restrict__ bias)
{
    __shared__ u16 As[128 * 64];
    __shared__ u16 Bs[128 * 64];

    const int NT = 4;
    const int per = gridDim.x >> 3;
    const int lin = (blockIdx.x & 7) * per + (blockIdx.x >> 3);
    const int nt = lin % NT, mt = lin / NT;
    const int m0 = mt * 128, n0 = nt * 128;

    const int tid  = threadIdx.x;
    const int lane = tid & 63;
    const int wid  = tid >> 6;
    const int wr = wid >> 1, wc = wid & 1;

    const int srow = lane >> 3;
    const int scol = (lane & 7) * 8;

    f32x4 acc[4][4] = {};

    for (int kt = 0; kt < 24; ++kt) {
        const int akk = 1024 + kt * 64;
        const int bkk = kt * 64;
#pragma unroll
        for (int q = 0; q < 4; ++q) {
            const int c = wid * 4 + q;
            gld_lds16(Os + (size_t)(m0 + c * 8 + srow) * 3072 + akk + scol, &As[c * 512]);
            gld_lds16(BT + (size_t)(n0 + c * 8 + srow) * 1536 + bkk + scol, &Bs[c * 512]);
        }
        __syncthreads();
#pragma unroll
        for (int ks = 0; ks < 2; ++ks) {
            const int ko = ks * 32 + (lane >> 4) * 8;
            const int rl = lane & 15;
            f16x8 af[4], bfr[4];
#pragma unroll
            for (int i = 0; i < 4; ++i) {
                af[i]  = *(const f16x8*)&As[(wr * 64 + i * 16 + rl) * 64 + ko];
                bfr[i] = *(const f16x8*)&Bs[(wc * 64 + i * 16 + rl) * 64 + ko];
            }
#pragma unroll
            for (int i = 0; i < 4; ++i)
#pragma unroll
                for (int j = 0; j < 4; ++j)
                    acc[i][j] = __builtin_amdgcn_mfma_f32_16x16x32_f16(af[i], bfr[j], acc[i][j], 0, 0, 0);
        }
        __syncthreads();
    }

    const int lr = (lane >> 4) * 4, lc = lane & 15;
#pragma unroll
    for (int i = 0; i < 4; ++i) {
        const int row = m0 + wr * 64 + i * 16 + lr;
#pragma unroll
        for (int j = 0; j < 4; ++j) {
            const int col = n0 + wc * 64 + j * 16 + lc;
            const float badd = bias[col];
            float* cp = C + (size_t)row * 512 + col;
#pragma unroll
            for (int v = 0; v < 4; ++v) cp[(size_t)v * 512] = acc[i][j][v] + badd;
        }
    }
}

// --------------------------- launcher -------------------------------------
extern "C" void kernel_launch(void* const* d_in, const int* in_sizes, int n_in,
                              void* d_out, int out_size, void* d_ws, size_t ws_size,
                              hipStream_t stream) {
    const float* x      = (const float*)d_in[0];
    const float* w_qkv  = (const float*)d_in[1];
    const float* w_proj = (const float*)d_in[2];
    const float* b_proj = (const float*)d_in[3];
    const float* relpos = (const float*)d_in[4];
    const float* qn_w   = (const float*)d_in[5];
    const float* kn_w   = (const float*)d_in[6];

    const size_t QKV_BYTES = (size_t)MTOK * 1536 * 4;   // 981,467,136
    const size_t BQT_BYTES = (size_t)1536 * 1536 * 2;   //   4,718,592
    const size_t BPT_BYTES = (size_t)512 * 1536 * 2;    //   1,572,864
    const size_t WS_NEEDED = QKV_BYTES + BQT_BYTES + BPT_BYTES;  // 987,758,592

    if (ws_size < WS_NEEDED) {
        // ws too small: emit sentinel so the bench reports absmax ~1e30
        sentinel_kernel<<<2048, 256, 0, stream>>>((float*)d_out, out_size);
        return;
    }

    char* ws = (char*)d_ws;
    float* qkv = (float*)ws;
    u16*   BqT = (u16*)(ws + QKV_BYTES);
    u16*   BpT = (u16*)(ws + QKV_BYTES + BQT_BYTES);

    split_w_kernel<<<1024, 256, 0, stream>>>(w_qkv, BqT, 1536);
    split_w_kernel<<<512, 256, 0, stream>>>(w_proj, BpT, 512);

    gemm_qkv<<<1248 * 12, 256, 0, stream>>>(x, BqT, qkv);

    attn_kernel<<<4 * NROWS, 512, 0, stream>>>(qkv, relpos, qn_w, kn_w);

    gemm_proj<<<1248 * 4, 256, 0, stream>>>((const u16*)qkv, BpT, (float*)d_out, b_proj);
}